// Round 8
// baseline (303.286 us; speedup 1.0000x reference)
//
#include <hip/hip_runtime.h>
#include <hip/hip_bf16.h>

#define Bv 32
#define Nv 4096
#define Dv 64
#define Hv 64
#define Fv 128
#define Ev 65536
#define Sv 2
#define Ov 128
#define Mv 5

typedef unsigned int uint;
using short8  = __attribute__((ext_vector_type(8))) short;
using floatx4 = __attribute__((ext_vector_type(4))) float;
using f32x2   = __attribute__((ext_vector_type(2))) float;
using uintx4  = __attribute__((ext_vector_type(4))) uint;

#define AS1 __attribute__((address_space(1)))
#define AS3 __attribute__((address_space(3)))

__device__ __forceinline__ float bflo(uint u){ uint v = u << 16; float f; __builtin_memcpy(&f, &v, 4); return f; }
__device__ __forceinline__ float bfhi(uint u){ uint v = u & 0xffff0000u; float f; __builtin_memcpy(&f, &v, 4); return f; }
__device__ __forceinline__ unsigned short f2bf(float f){
  uint x; __builtin_memcpy(&x, &f, 4);
  x += 0x7fffu + ((x >> 16) & 1u);           // RNE
  return (unsigned short)(x >> 16);
}
__device__ __forceinline__ uint bfpack(float a, float b){
  return (uint)f2bf(a) | ((uint)f2bf(b) << 16);
}

// async 16B global->LDS (m97-verified width). lds base must be wave-uniform;
// HW deposits lane L at base + L*16.
__device__ __forceinline__ void ld16(void* lds, const void* g){
  __builtin_amdgcn_global_load_lds((const AS1 uint*)g, (AS3 uint*)lds, 16, 0, 0);
}

// ---------------- CSR build ----------------
__global__ void k_hist(const int* __restrict__ rows, int* __restrict__ deg){
  int i = blockIdx.x * 256 + threadIdx.x;           // [0, S*E)
  int s = i >> 16;                                  // E = 65536
  int r = rows[i];
  atomicAdd(&deg[s * Nv + r], 1);
}

__global__ void k_scan(const int* __restrict__ deg, int* __restrict__ rowptr, int* __restrict__ cursor){
  __shared__ int part[256];
  __shared__ int sbase[256];
  int t = threadIdx.x;
  for(int s = 0; s < Sv; s++){
    int loc[16]; int sum = 0;
    #pragma unroll
    for(int i = 0; i < 16; i++){ loc[i] = deg[s * Nv + t * 16 + i]; sum += loc[i]; }
    part[t] = sum;
    __syncthreads();
    if(t == 0){ int run = 0; for(int i = 0; i < 256; i++){ int v = part[i]; sbase[i] = run; run += v; } }
    __syncthreads();
    int run = sbase[t];
    #pragma unroll
    for(int i = 0; i < 16; i++){
      int idx = t * 16 + i;
      rowptr[s * (Nv + 1) + idx] = run;
      cursor[s * Nv + idx] = run;
      run += loc[i];
    }
    if(t == 255) rowptr[s * (Nv + 1) + Nv] = run;
    __syncthreads();
  }
}

// pack (col:u16 low, bf16(val):u16 high) -> 4 B/edge
__global__ void k_scatter(const int* __restrict__ rows, const int* __restrict__ cols,
                          const float* __restrict__ vals, int* __restrict__ cursor,
                          uint* __restrict__ pk){
  int i = blockIdx.x * 256 + threadIdx.x;           // [0, S*E)
  int s = i >> 16;
  int r = rows[i];
  int p = atomicAdd(&cursor[s * Nv + r], 1);
  pk[(s << 16) + p] = (uint)cols[i] | ((uint)f2bf(vals[i]) << 16);
}

// ---------------- build X0 (bf16 [b][n][f] + fp8 copy) + weights, fused ----------------
__global__ void k_buildx0(const float* __restrict__ inp, const float* __restrict__ st,
                          uint* __restrict__ X0bf, uint* __restrict__ X08,
                          const float* __restrict__ wg, unsigned short* __restrict__ Wb){
  if(blockIdx.x >= 4096){                           // weight repack tail: 320 blocks
    int t = (blockIdx.x - 4096) * 256 + threadIdx.x;  // [0, Mv*Ov*Fv)
    int f = t & (Fv - 1);
    int o = (t >> 7) & (Ov - 1);
    int m = t >> 14;
    Wb[t] = f2bf(wg[(f * Mv + m) * Ov + o]);
    return;
  }
  const int t = blockIdx.x * 256 + threadIdx.x;     // [0, B*N*8)
  const int c = t & 7;                              // 16-float chunk
  const int n = (t >> 3) & (Nv - 1);
  const int b = t >> 15;
  const float* src = (c < 4) ? (inp + ((size_t)b * Nv + n) * 64 + c * 16)
                             : (st  + ((size_t)b * Nv + n) * 64 + (c - 4) * 16);
  float v[16];
  #pragma unroll
  for(int q = 0; q < 4; q++){
    float4 f4 = *(const float4*)(src + q * 4);
    v[q * 4 + 0] = f4.x; v[q * 4 + 1] = f4.y; v[q * 4 + 2] = f4.z; v[q * 4 + 3] = f4.w;
  }
  const size_t base = (size_t)b * Nv + n;
  uint bfw[8];
  #pragma unroll
  for(int q = 0; q < 8; q++) bfw[q] = bfpack(v[2 * q], v[2 * q + 1]);
  *(uintx4*)(X0bf + base * 64 + c * 8)     = *(uintx4*)(bfw);
  *(uintx4*)(X0bf + base * 64 + c * 8 + 4) = *(uintx4*)(bfw + 4);
  uint f8w[4];
  #pragma unroll
  for(int q = 0; q < 4; q++){
    int w = __builtin_amdgcn_cvt_pk_fp8_f32(v[4 * q + 0], v[4 * q + 1], 0, false);
    w     = __builtin_amdgcn_cvt_pk_fp8_f32(v[4 * q + 2], v[4 * q + 3], w, true);
    f8w[q] = (uint)w;
  }
  *(uintx4*)(X08 + base * 32 + c * 4) = *(uintx4*)(f8w);
}

// ---------------- SpMM v7: 2-deep software-pipelined gather stages ----------------
// Per 8-edge stage the old loop issued 8 gathers THEN consumed them (runtime
// trip count -> compiler can't pipeline): every stage exposed a full L2 latency.
// Now stage t+1's gathers are issued before consuming stage t, with statically
// named double buffers gA/gB (rule #20: no runtime-indexed reg arrays).
// xprev (x0) load hoisted above the edge loop so its latency hides too.
__launch_bounds__(256)
__global__ void k_spmm3(const uint* __restrict__ src8, const uint* __restrict__ src8B,
                        uint* __restrict__ dstA, uint* __restrict__ dstB,
                        uint* __restrict__ dA8, uint* __restrict__ dB8,
                        const uint* __restrict__ xprev,
                        const int* __restrict__ rowptr, const uint* __restrict__ pk,
                        const int two_supports){
  const int lane = threadIdx.x & 63;
  const int wv   = threadIdx.x >> 6;
  const int bid = blockIdx.x;
  int s, pg, rb;
  if(two_supports){ s = (bid >> 2) & 1; pg = bid & 3; rb = bid >> 3; }  // XCD = s*4+pg
  else            { s = 0;             pg = bid & 3; rb = bid >> 2; }
  const int r  = rb * 4 + wv;
  const int p  = pg * 8 + (lane >> 3);              // plane 0..31
  const int cB = (lane & 7) * 16;                   // byte offset in 128B fp8 row
  const int* rp   = rowptr + s * (Nv + 1);
  const uint* pks = pk + (s << 16);
  const int j0 = rp[r], j1 = rp[r + 1];
  const uint8_t* srcs = (const uint8_t*)(s ? src8B : src8);
  const uint laneoff = (uint)p * (Nv * 128) + (uint)cB;   // per-lane const, <16MiB
  uint* dst = s ? dstB : dstA;
  uint* d8  = s ? dB8  : dA8;
  const size_t obase = (size_t)p * Nv + r;

  // hoist xprev load: issued before the gather loop, consumed after it
  uint pw[8];
  if(xprev){
    const uint* pv = xprev + obase * 64 + (cB >> 1);
    *(uintx4*)(pw)     = *(const uintx4*)(pv);
    *(uintx4*)(pw + 4) = *(const uintx4*)(pv + 4);
  }

  f32x2 acc2[8];                                    // acc2[k] = {f(2k), f(2k+1)}
  #pragma unroll
  for(int k = 0; k < 8; k++) acc2[k] = (f32x2){0.f, 0.f};

  for(int j = j0; j < j1; j += 64){
    int rem = j1 - j; if(rem > 64) rem = 64;
    const uint e = (lane < rem) ? pks[j + lane] : 0u;   // pad: val=0, col=0
    const int nst = (rem + 7) >> 3;                     // 8-edge stages (zero-padded tail)

    uintx4 gA[8], gB[8]; float vA[8], vB[8];
    #define GLOAD(G, V, T)                                                        \
      _Pragma("unroll")                                                           \
      for(int u = 0; u < 8; u++){                                                 \
        const uint eu = __builtin_amdgcn_readlane(e, (T) + u);  /* SGPR edge */   \
        V[u] = bfhi(eu);                                                          \
        const uint8_t* sb = srcs + ((size_t)(eu & 0xffffu) << 7);                 \
        G[u] = *(const uintx4*)(sb + laneoff);                                    \
      }
    #define GCONS(G, V)                                                           \
      _Pragma("unroll")                                                           \
      for(int u = 0; u < 8; u++){                                                 \
        const f32x2 v2 = {V[u], V[u]};                                            \
        _Pragma("unroll")                                                         \
        for(int d = 0; d < 4; d++){                                               \
          f32x2 lo = __builtin_amdgcn_cvt_pk_f32_fp8((int)G[u][d], false);        \
          f32x2 hi = __builtin_amdgcn_cvt_pk_f32_fp8((int)G[u][d], true);         \
          acc2[d * 2 + 0] = __builtin_elementwise_fma(v2, lo, acc2[d * 2 + 0]);   \
          acc2[d * 2 + 1] = __builtin_elementwise_fma(v2, hi, acc2[d * 2 + 1]);   \
        }                                                                         \
      }

    GLOAD(gA, vA, 0)
    for(int st = 0; st < nst; st += 2){
      if(st + 1 < nst) GLOAD(gB, vB, (st + 1) * 8)    // prefetch next stage
      GCONS(gA, vA)                                   // consume current
      if(st + 1 < nst){
        if(st + 2 < nst) GLOAD(gA, vA, (st + 2) * 8)
        GCONS(gB, vB)
      }
    }
    #undef GLOAD
    #undef GCONS
  }

  if(xprev){                                        // x2 = 2*A*x1 - x0
    #pragma unroll
    for(int q = 0; q < 8; q++){
      const f32x2 prev = {bflo(pw[q]), bfhi(pw[q])};
      acc2[q] = 2.f * acc2[q] - prev;
    }
  }
  uint bfw[8];
  #pragma unroll
  for(int q = 0; q < 8; q++) bfw[q] = bfpack(acc2[q][0], acc2[q][1]);
  uint* db = dst + obase * 64 + (cB >> 1);
  __builtin_nontemporal_store(*(uintx4*)(bfw),     (uintx4*)(db));
  __builtin_nontemporal_store(*(uintx4*)(bfw + 4), (uintx4*)(db + 4));
  if(d8){
    uint f8w[4];
    #pragma unroll
    for(int q = 0; q < 4; q++){
      int w = __builtin_amdgcn_cvt_pk_fp8_f32(acc2[2 * q][0],     acc2[2 * q][1],     0, false);
      w     = __builtin_amdgcn_cvt_pk_fp8_f32(acc2[2 * q + 1][0], acc2[2 * q + 1][1], w, true);
      f8w[q] = (uint)w;
    }
    __builtin_nontemporal_store(*(uintx4*)(f8w), (uintx4*)(d8 + obase * 32 + (cB >> 2)));
  }
}

// ---------------- GEMM: 2-phase double-buffered pipeline (proven: 60-64us; FROZEN) ----------------
// 128x128 tile, BK=32, 20 flat K-steps (5 matrices x 4). One barrier/step;
// STAGE(t+1) issued before ds_read+MFMA of step t. A AND B both via LDS
// (B-direct-to-reg variant spilled: +53MB scratch writes at VGPR=64 cap;
// 3-buffer counted-vmcnt variant lost occupancy: 73us).
__launch_bounds__(256, 4)
__global__ void k_gemm(const unsigned short* __restrict__ X0,
                       const unsigned short* __restrict__ X1a,
                       const unsigned short* __restrict__ X2a,
                       const unsigned short* __restrict__ X1b,
                       const unsigned short* __restrict__ X2b,
                       const unsigned short* __restrict__ Wb,
                       const float* __restrict__ bias,
                       float* __restrict__ out){
  __shared__ unsigned short Asm[2][128 * 32];
  __shared__ unsigned short Bsm[2][128 * 32];
  const unsigned short* Am[5] = {X0, X1a, X2a, X1b, X2b};
  const int tid  = threadIdx.x;
  const int lane = tid & 63, wv = tid >> 6;
  const int wm = wv >> 1, wn = wv & 1;
  const int lrow = lane & 15, quad = lane >> 4;
  const size_t r0 = (size_t)blockIdx.x * 128;

  // staging geometry (per thread: 1 A-16B + 1 B-16B per p-phase, p=0,1)
  const int row0 = (wv * 64 + lane) >> 2, seg0 = (wv * 64 + lane) & 3;             // p=0
  const int row1 = (256 + wv * 64 + lane) >> 2, seg1 = (256 + wv * 64 + lane) & 3; // p=1
  const int ldsb0 = (wv * 64) * 8;           // wave-uniform LDS short-offset, p=0
  const int ldsb1 = (256 + wv * 64) * 8;     // p=1

  floatx4 acc[4][4] = {};

  #define STAGE(stp, bufi)                                                        \
    do {                                                                          \
      const int m_ = (stp) >> 2, kk_ = ((stp) & 3) * 32;                          \
      const unsigned short* Ab_ = Am[m_] + r0 * Fv;                               \
      const unsigned short* Bb_ = Wb + m_ * (Ov * Fv);                            \
      ld16(&Asm[bufi][ldsb0], Ab_ + (size_t)row0 * Fv + kk_ + seg0 * 8);          \
      ld16(&Bsm[bufi][ldsb0], Bb_ + row0 * Fv + kk_ + seg0 * 8);                  \
      ld16(&Asm[bufi][ldsb1], Ab_ + (size_t)row1 * Fv + kk_ + seg1 * 8);          \
      ld16(&Bsm[bufi][ldsb1], Bb_ + row1 * Fv + kk_ + seg1 * 8);                  \
    } while (0)

  STAGE(0, 0);
  __syncthreads();                                   // drains vmcnt(0)

  #pragma unroll
  for(int step = 0; step < 20; ++step){
    const int buf = step & 1;
    if(step + 1 < 20) STAGE(step + 1, buf ^ 1);      // prefetch next tile (in flight during compute)
    short8 af[4], bfr[4];
    #pragma unroll
    for(int t = 0; t < 4; t++){
      af[t]  = *(const short8*)(&Asm[buf][(wm * 64 + t * 16 + lrow) * 32 + quad * 8]);
      bfr[t] = *(const short8*)(&Bsm[buf][(wn * 64 + t * 16 + lrow) * 32 + quad * 8]);
    }
    __builtin_amdgcn_s_setprio(1);
    #pragma unroll
    for(int ti = 0; ti < 4; ti++)
      #pragma unroll
      for(int tj = 0; tj < 4; tj++)
        acc[ti][tj] = __builtin_amdgcn_mfma_f32_16x16x32_bf16(af[ti], bfr[tj], acc[ti][tj], 0, 0, 0);
    __builtin_amdgcn_s_setprio(0);
    if(step + 1 < 20) __syncthreads();               // one barrier/step: drains prefetch + protects buf swap
  }
  #undef STAGE

  #pragma unroll
  for(int ti = 0; ti < 4; ti++){
    #pragma unroll
    for(int tj = 0; tj < 4; tj++){
      const int col = wn * 64 + tj * 16 + lrow;
      const float bv = bias[col];
      const size_t rbase = r0 + wm * 64 + ti * 16 + quad * 4;
      #pragma unroll
      for(int t = 0; t < 4; t++){
        __builtin_nontemporal_store(acc[ti][tj][t] + bv, &out[(rbase + t) * Ov + col]);
      }
    }
  }
}

extern "C" void kernel_launch(void* const* d_in, const int* in_sizes, int n_in,
                              void* d_out, int out_size, void* d_ws, size_t ws_size,
                              hipStream_t stream) {
  (void)in_sizes; (void)n_in; (void)out_size; (void)ws_size;
  const float* inp  = (const float*)d_in[0];
  const float* st   = (const float*)d_in[1];
  const int*   rows = (const int*)d_in[2];
  const int*   cols = (const int*)d_in[3];
  const float* vals = (const float*)d_in[4];
  const float* wght = (const float*)d_in[5];
  const float* bias = (const float*)d_in[6];
  float* out = (float*)d_out;

  char* w = (char*)d_ws;
  const size_t SZX  = (size_t)Bv * Nv * Fv * 2;     // 32 MiB bf16 matrix
  const size_t SZX8 = (size_t)Bv * Nv * Fv;         // 16 MiB fp8 matrix
  unsigned short* X0  = (unsigned short*)(w);
  unsigned short* X1a = (unsigned short*)(w + SZX);
  unsigned short* X2a = (unsigned short*)(w + 2 * SZX);
  unsigned short* X1b = (unsigned short*)(w + 3 * SZX);
  unsigned short* X2b = (unsigned short*)(w + 4 * SZX);
  uint* X08  = (uint*)(w + 5 * SZX);
  uint* X1a8 = (uint*)(w + 5 * SZX + SZX8);
  uint* X1b8 = (uint*)(w + 5 * SZX + 2 * SZX8);
  unsigned short* Wb = (unsigned short*)(w + 5 * SZX + 3 * SZX8);
  char* p2 = w + 5 * SZX + 3 * SZX8 + 262144;
  int* deg    = (int*)p2;
  int* cursor = deg + Sv * Nv;
  int* rowptr = cursor + Sv * Nv;
  uint* pk    = (uint*)(rowptr + Sv * (Nv + 1) + 62);
  // ws use: 160 MiB bf16 + 48 MiB fp8 + ~2 MiB misc ~= 210 MiB

  hipMemsetAsync(deg, 0, Sv * Nv * sizeof(int), stream);
  k_hist<<<Sv * Ev / 256, 256, 0, stream>>>(rows, deg);
  k_scan<<<1, 256, 0, stream>>>(deg, rowptr, cursor);
  k_scatter<<<Sv * Ev / 256, 256, 0, stream>>>(rows, cols, vals, cursor, pk);
  k_buildx0<<<4096 + (Mv * Ov * Fv) / 256, 256, 0, stream>>>(inp, st, (uint*)X0, X08, wght, Wb);

  // step 1: x1 = A_s x0, both supports in one launch
  k_spmm3<<<8192, 256, 0, stream>>>(X08, X08, (uint*)X1a, (uint*)X1b, X1a8, X1b8,
                                    (const uint*)nullptr, rowptr, pk, 1);
  // step 2: x2 = 2 A_s x1 - x0, both supports in ONE launch (independent chains)
  k_spmm3<<<8192, 256, 0, stream>>>(X1a8, X1b8, (uint*)X2a, (uint*)X2b, nullptr, nullptr,
                                    (const uint*)X0, rowptr, pk, 1);

  k_gemm<<<(Bv * Nv) / 128, 256, 0, stream>>>(X0, X1a, X2a, X1b, X2b, Wb, bias, out);
}

// Round 9
// 286.725 us; speedup vs baseline: 1.0578x; 1.0578x over previous
//
#include <hip/hip_runtime.h>
#include <hip/hip_bf16.h>

#define Bv 32
#define Nv 4096
#define Dv 64
#define Hv 64
#define Fv 128
#define Ev 65536
#define Sv 2
#define Ov 128
#define Mv 5

typedef unsigned int uint;
using short8  = __attribute__((ext_vector_type(8))) short;
using floatx4 = __attribute__((ext_vector_type(4))) float;
using f32x2   = __attribute__((ext_vector_type(2))) float;
using uintx4  = __attribute__((ext_vector_type(4))) uint;

#define AS1 __attribute__((address_space(1)))
#define AS3 __attribute__((address_space(3)))

__device__ __forceinline__ float bflo(uint u){ uint v = u << 16; float f; __builtin_memcpy(&f, &v, 4); return f; }
__device__ __forceinline__ float bfhi(uint u){ uint v = u & 0xffff0000u; float f; __builtin_memcpy(&f, &v, 4); return f; }
__device__ __forceinline__ unsigned short f2bf(float f){
  uint x; __builtin_memcpy(&x, &f, 4);
  x += 0x7fffu + ((x >> 16) & 1u);           // RNE
  return (unsigned short)(x >> 16);
}
__device__ __forceinline__ uint bfpack(float a, float b){
  return (uint)f2bf(a) | ((uint)f2bf(b) << 16);
}

// async 16B global->LDS (m97-verified width). lds base must be wave-uniform;
// HW deposits lane L at base + L*16.
__device__ __forceinline__ void ld16(void* lds, const void* g){
  __builtin_amdgcn_global_load_lds((const AS1 uint*)g, (AS3 uint*)lds, 16, 0, 0);
}

// ---------------- CSR build ----------------
__global__ void k_hist(const int* __restrict__ rows, int* __restrict__ deg){
  int i = blockIdx.x * 256 + threadIdx.x;           // [0, S*E)
  int s = i >> 16;                                  // E = 65536
  int r = rows[i];
  atomicAdd(&deg[s * Nv + r], 1);
}

__global__ void k_scan(const int* __restrict__ deg, int* __restrict__ rowptr, int* __restrict__ cursor){
  __shared__ int part[256];
  __shared__ int sbase[256];
  int t = threadIdx.x;
  for(int s = 0; s < Sv; s++){
    int loc[16]; int sum = 0;
    #pragma unroll
    for(int i = 0; i < 16; i++){ loc[i] = deg[s * Nv + t * 16 + i]; sum += loc[i]; }
    part[t] = sum;
    __syncthreads();
    if(t == 0){ int run = 0; for(int i = 0; i < 256; i++){ int v = part[i]; sbase[i] = run; run += v; } }
    __syncthreads();
    int run = sbase[t];
    #pragma unroll
    for(int i = 0; i < 16; i++){
      int idx = t * 16 + i;
      rowptr[s * (Nv + 1) + idx] = run;
      cursor[s * Nv + idx] = run;
      run += loc[i];
    }
    if(t == 255) rowptr[s * (Nv + 1) + Nv] = run;
    __syncthreads();
  }
}

// pack (col:u16 low, bf16(val):u16 high) -> 4 B/edge
__global__ void k_scatter(const int* __restrict__ rows, const int* __restrict__ cols,
                          const float* __restrict__ vals, int* __restrict__ cursor,
                          uint* __restrict__ pk){
  int i = blockIdx.x * 256 + threadIdx.x;           // [0, S*E)
  int s = i >> 16;
  int r = rows[i];
  int p = atomicAdd(&cursor[s * Nv + r], 1);
  pk[(s << 16) + p] = (uint)cols[i] | ((uint)f2bf(vals[i]) << 16);
}

// ---------------- build X0 (bf16 [b][n][f] + fp8 copy) + weights, fused ----------------
__global__ void k_buildx0(const float* __restrict__ inp, const float* __restrict__ st,
                          uint* __restrict__ X0bf, uint* __restrict__ X08,
                          const float* __restrict__ wg, unsigned short* __restrict__ Wb){
  if(blockIdx.x >= 4096){                           // weight repack tail: 320 blocks
    int t = (blockIdx.x - 4096) * 256 + threadIdx.x;  // [0, Mv*Ov*Fv)
    int f = t & (Fv - 1);
    int o = (t >> 7) & (Ov - 1);
    int m = t >> 14;
    Wb[t] = f2bf(wg[(f * Mv + m) * Ov + o]);
    return;
  }
  const int t = blockIdx.x * 256 + threadIdx.x;     // [0, B*N*8)
  const int c = t & 7;                              // 16-float chunk
  const int n = (t >> 3) & (Nv - 1);
  const int b = t >> 15;
  const float* src = (c < 4) ? (inp + ((size_t)b * Nv + n) * 64 + c * 16)
                             : (st  + ((size_t)b * Nv + n) * 64 + (c - 4) * 16);
  float v[16];
  #pragma unroll
  for(int q = 0; q < 4; q++){
    float4 f4 = *(const float4*)(src + q * 4);
    v[q * 4 + 0] = f4.x; v[q * 4 + 1] = f4.y; v[q * 4 + 2] = f4.z; v[q * 4 + 3] = f4.w;
  }
  const size_t base = (size_t)b * Nv + n;
  uint bfw[8];
  #pragma unroll
  for(int q = 0; q < 8; q++) bfw[q] = bfpack(v[2 * q], v[2 * q + 1]);
  *(uintx4*)(X0bf + base * 64 + c * 8)     = *(uintx4*)(bfw);
  *(uintx4*)(X0bf + base * 64 + c * 8 + 4) = *(uintx4*)(bfw + 4);
  uint f8w[4];
  #pragma unroll
  for(int q = 0; q < 4; q++){
    int w = __builtin_amdgcn_cvt_pk_fp8_f32(v[4 * q + 0], v[4 * q + 1], 0, false);
    w     = __builtin_amdgcn_cvt_pk_fp8_f32(v[4 * q + 2], v[4 * q + 3], w, true);
    f8w[q] = (uint)w;
  }
  *(uintx4*)(X08 + base * 32 + c * 4) = *(uintx4*)(f8w);
}

// ---------------- SpMM v8: persistent XCD-pinned blocks + cacheable dst ----------------
// Grid = 1024 blocks = exact co-residency (4 blocks/CU): every block lives the
// whole kernel, so bid&7 -> XCD holds (8192-block version drifted as retiring
// blocks were backfilled). Block owns slice (s,pg)=(xcd>>2,xcd&3): gather
// working set = 8 planes x 4096 x 128B = 4 MB = one XCD's L2, pinned.
// dst stores are now REGULAR (not nontemporal): fp8 dst is re-gathered by the
// next spmm, bf16 dst is read by gemm - streaming them past L2/L3 forced HBM
// round-trips (FETCH 106 MB vs 32 MB compulsory).
__launch_bounds__(256)
__global__ void k_spmm3(const uint* __restrict__ src8, const uint* __restrict__ src8B,
                        uint* __restrict__ dstA, uint* __restrict__ dstB,
                        uint* __restrict__ dA8, uint* __restrict__ dB8,
                        const uint* __restrict__ xprev,
                        const int* __restrict__ rowptr, const uint* __restrict__ pk){
  const int lane = threadIdx.x & 63;
  const int wv   = threadIdx.x >> 6;
  const int xcd  = blockIdx.x & 7;
  const int s = xcd >> 2, pg = xcd & 3;             // slice pinned to this XCD
  const int rb0 = blockIdx.x >> 3;                  // [0,128)
  const int p  = pg * 8 + (lane >> 3);              // plane 0..31
  const int cB = (lane & 7) * 16;                   // byte offset in 128B fp8 row
  const int* rp   = rowptr + s * (Nv + 1);
  const uint* pks = pk + (s << 16);
  const uint8_t* srcs = (const uint8_t*)(s ? src8B : src8);
  const uint laneoff = (uint)p * (Nv * 128) + (uint)cB;   // per-lane const, <16MiB
  uint* dst = s ? dstB : dstA;
  uint* d8  = s ? dB8  : dA8;

  for(int rb = rb0; rb < 1024; rb += 128){          // persistent: 8 row-blocks/block
    const int r = rb * 4 + wv;
    const int j0 = rp[r], j1 = rp[r + 1];

    f32x2 acc2[8];                                  // acc2[k] = {f(2k), f(2k+1)}
    #pragma unroll
    for(int k = 0; k < 8; k++) acc2[k] = (f32x2){0.f, 0.f};

    for(int j = j0; j < j1; j += 64){
      int rem = j1 - j; if(rem > 64) rem = 64;
      const uint e = (lane < rem) ? pks[j + lane] : 0u;   // pad: val=0, col=0
      for(int t = 0; t < rem; t += 8){
        uintx4 g[8]; float v[8];
        #pragma unroll
        for(int u = 0; u < 8; u++){
          const uint eu = __builtin_amdgcn_readlane(e, t + u);   // SGPR edge word
          v[u] = bfhi(eu);                                       // scalar until FMA
          const uint8_t* sb = srcs + ((size_t)(eu & 0xffffu) << 7);  // s_base + col*128B
          g[u] = *(const uintx4*)(sb + laneoff);
        }
        #pragma unroll
        for(int u = 0; u < 8; u++){
          const f32x2 v2 = {v[u], v[u]};
          #pragma unroll
          for(int d = 0; d < 4; d++){
            f32x2 lo = __builtin_amdgcn_cvt_pk_f32_fp8((int)g[u][d], false);
            f32x2 hi = __builtin_amdgcn_cvt_pk_f32_fp8((int)g[u][d], true);
            acc2[d * 2 + 0] = __builtin_elementwise_fma(v2, lo, acc2[d * 2 + 0]);
            acc2[d * 2 + 1] = __builtin_elementwise_fma(v2, hi, acc2[d * 2 + 1]);
          }
        }
      }
    }

    const size_t obase = (size_t)p * Nv + r;
    if(xprev){                                      // x2 = 2*A*x1 - x0
      const uint* pv = xprev + obase * 64 + (cB >> 1);
      uint pw[8];
      *(uintx4*)(pw)     = *(const uintx4*)(pv);
      *(uintx4*)(pw + 4) = *(const uintx4*)(pv + 4);
      #pragma unroll
      for(int q = 0; q < 8; q++){
        const f32x2 prev = {bflo(pw[q]), bfhi(pw[q])};
        acc2[q] = 2.f * acc2[q] - prev;
      }
    }
    uint bfw[8];
    #pragma unroll
    for(int q = 0; q < 8; q++) bfw[q] = bfpack(acc2[q][0], acc2[q][1]);
    uint* db = dst + obase * 64 + (cB >> 1);
    *(uintx4*)(db)     = *(uintx4*)(bfw);           // regular store: gemm re-reads
    *(uintx4*)(db + 4) = *(uintx4*)(bfw + 4);
    if(d8){
      uint f8w[4];
      #pragma unroll
      for(int q = 0; q < 4; q++){
        int w = __builtin_amdgcn_cvt_pk_fp8_f32(acc2[2 * q][0],     acc2[2 * q][1],     0, false);
        w     = __builtin_amdgcn_cvt_pk_fp8_f32(acc2[2 * q + 1][0], acc2[2 * q + 1][1], w, true);
        f8w[q] = (uint)w;
      }
      *(uintx4*)(d8 + obase * 32 + (cB >> 2)) = *(uintx4*)(f8w);  // spmm2 re-gathers
    }
  }
}

// ---------------- GEMM: 2-phase double-buffered pipeline (proven: 60-64us; FROZEN) ----------------
// 128x128 tile, BK=32, 20 flat K-steps (5 matrices x 4). One barrier/step;
// STAGE(t+1) issued before ds_read+MFMA of step t. A AND B both via LDS
// (B-direct-to-reg variant spilled: +53MB scratch writes at VGPR=64 cap;
// 3-buffer counted-vmcnt variant lost occupancy: 73us).
__launch_bounds__(256, 4)
__global__ void k_gemm(const unsigned short* __restrict__ X0,
                       const unsigned short* __restrict__ X1a,
                       const unsigned short* __restrict__ X2a,
                       const unsigned short* __restrict__ X1b,
                       const unsigned short* __restrict__ X2b,
                       const unsigned short* __restrict__ Wb,
                       const float* __restrict__ bias,
                       float* __restrict__ out){
  __shared__ unsigned short Asm[2][128 * 32];
  __shared__ unsigned short Bsm[2][128 * 32];
  const unsigned short* Am[5] = {X0, X1a, X2a, X1b, X2b};
  const int tid  = threadIdx.x;
  const int lane = tid & 63, wv = tid >> 6;
  const int wm = wv >> 1, wn = wv & 1;
  const int lrow = lane & 15, quad = lane >> 4;
  const size_t r0 = (size_t)blockIdx.x * 128;

  // staging geometry (per thread: 1 A-16B + 1 B-16B per p-phase, p=0,1)
  const int row0 = (wv * 64 + lane) >> 2, seg0 = (wv * 64 + lane) & 3;             // p=0
  const int row1 = (256 + wv * 64 + lane) >> 2, seg1 = (256 + wv * 64 + lane) & 3; // p=1
  const int ldsb0 = (wv * 64) * 8;           // wave-uniform LDS short-offset, p=0
  const int ldsb1 = (256 + wv * 64) * 8;     // p=1

  floatx4 acc[4][4] = {};

  #define STAGE(stp, bufi)                                                        \
    do {                                                                          \
      const int m_ = (stp) >> 2, kk_ = ((stp) & 3) * 32;                          \
      const unsigned short* Ab_ = Am[m_] + r0 * Fv;                               \
      const unsigned short* Bb_ = Wb + m_ * (Ov * Fv);                            \
      ld16(&Asm[bufi][ldsb0], Ab_ + (size_t)row0 * Fv + kk_ + seg0 * 8);          \
      ld16(&Bsm[bufi][ldsb0], Bb_ + row0 * Fv + kk_ + seg0 * 8);                  \
      ld16(&Asm[bufi][ldsb1], Ab_ + (size_t)row1 * Fv + kk_ + seg1 * 8);          \
      ld16(&Bsm[bufi][ldsb1], Bb_ + row1 * Fv + kk_ + seg1 * 8);                  \
    } while (0)

  STAGE(0, 0);
  __syncthreads();                                   // drains vmcnt(0)

  #pragma unroll
  for(int step = 0; step < 20; ++step){
    const int buf = step & 1;
    if(step + 1 < 20) STAGE(step + 1, buf ^ 1);      // prefetch next tile (in flight during compute)
    short8 af[4], bfr[4];
    #pragma unroll
    for(int t = 0; t < 4; t++){
      af[t]  = *(const short8*)(&Asm[buf][(wm * 64 + t * 16 + lrow) * 32 + quad * 8]);
      bfr[t] = *(const short8*)(&Bsm[buf][(wn * 64 + t * 16 + lrow) * 32 + quad * 8]);
    }
    __builtin_amdgcn_s_setprio(1);
    #pragma unroll
    for(int ti = 0; ti < 4; ti++)
      #pragma unroll
      for(int tj = 0; tj < 4; tj++)
        acc[ti][tj] = __builtin_amdgcn_mfma_f32_16x16x32_bf16(af[ti], bfr[tj], acc[ti][tj], 0, 0, 0);
    __builtin_amdgcn_s_setprio(0);
    if(step + 1 < 20) __syncthreads();               // one barrier/step: drains prefetch + protects buf swap
  }
  #undef STAGE

  #pragma unroll
  for(int ti = 0; ti < 4; ti++){
    #pragma unroll
    for(int tj = 0; tj < 4; tj++){
      const int col = wn * 64 + tj * 16 + lrow;
      const float bv = bias[col];
      const size_t rbase = r0 + wm * 64 + ti * 16 + quad * 4;
      #pragma unroll
      for(int t = 0; t < 4; t++){
        __builtin_nontemporal_store(acc[ti][tj][t] + bv, &out[(rbase + t) * Ov + col]);
      }
    }
  }
}

extern "C" void kernel_launch(void* const* d_in, const int* in_sizes, int n_in,
                              void* d_out, int out_size, void* d_ws, size_t ws_size,
                              hipStream_t stream) {
  (void)in_sizes; (void)n_in; (void)out_size; (void)ws_size;
  const float* inp  = (const float*)d_in[0];
  const float* st   = (const float*)d_in[1];
  const int*   rows = (const int*)d_in[2];
  const int*   cols = (const int*)d_in[3];
  const float* vals = (const float*)d_in[4];
  const float* wght = (const float*)d_in[5];
  const float* bias = (const float*)d_in[6];
  float* out = (float*)d_out;

  char* w = (char*)d_ws;
  const size_t SZX  = (size_t)Bv * Nv * Fv * 2;     // 32 MiB bf16 matrix
  const size_t SZX8 = (size_t)Bv * Nv * Fv;         // 16 MiB fp8 matrix
  unsigned short* X0  = (unsigned short*)(w);
  unsigned short* X1a = (unsigned short*)(w + SZX);
  unsigned short* X2a = (unsigned short*)(w + 2 * SZX);
  unsigned short* X1b = (unsigned short*)(w + 3 * SZX);
  unsigned short* X2b = (unsigned short*)(w + 4 * SZX);
  uint* X08  = (uint*)(w + 5 * SZX);
  uint* X1a8 = (uint*)(w + 5 * SZX + SZX8);
  uint* X1b8 = (uint*)(w + 5 * SZX + 2 * SZX8);
  unsigned short* Wb = (unsigned short*)(w + 5 * SZX + 3 * SZX8);
  char* p2 = w + 5 * SZX + 3 * SZX8 + 262144;
  int* deg    = (int*)p2;
  int* cursor = deg + Sv * Nv;
  int* rowptr = cursor + Sv * Nv;
  uint* pk    = (uint*)(rowptr + Sv * (Nv + 1) + 62);
  // ws use: 160 MiB bf16 + 48 MiB fp8 + ~2 MiB misc ~= 210 MiB

  hipMemsetAsync(deg, 0, Sv * Nv * sizeof(int), stream);
  k_hist<<<Sv * Ev / 256, 256, 0, stream>>>(rows, deg);
  k_scan<<<1, 256, 0, stream>>>(deg, rowptr, cursor);
  k_scatter<<<Sv * Ev / 256, 256, 0, stream>>>(rows, cols, vals, cursor, pk);
  k_buildx0<<<4096 + (Mv * Ov * Fv) / 256, 256, 0, stream>>>(inp, st, (uint*)X0, X08, wght, Wb);

  // step 1: x1 = A_s x0, both supports in one launch (persistent 1024-block grid)
  k_spmm3<<<1024, 256, 0, stream>>>(X08, X08, (uint*)X1a, (uint*)X1b, X1a8, X1b8,
                                    (const uint*)nullptr, rowptr, pk);
  // step 2: x2 = 2 A_s x1 - x0, both supports in one launch
  k_spmm3<<<1024, 256, 0, stream>>>(X1a8, X1b8, (uint*)X2a, (uint*)X2b, nullptr, nullptr,
                                    (const uint*)X0, rowptr, pk);

  k_gemm<<<(Bv * Nv) / 128, 256, 0, stream>>>(X0, X1a, X2a, X1b, X2b, Wb, bias, out);
}